// Round 1
// baseline (464.532 us; speedup 1.0000x reference)
//
#include <hip/hip_runtime.h>

#define N_NODESC 50000
#define E0C      800000
#define E_TOTC   850000
#define IN_CHC   128
#define HCC      128   // HEADS*HID
#define HEADSC   4
#define OUT_CHC  16
#define NEG_SLOPE 0.2f

__device__ __forceinline__ float lrelu(float v){ return v > 0.f ? v : NEG_SLOPE * v; }

__global__ void __launch_bounds__(256) k_zero(int* __restrict__ p, int n){
  int i = blockIdx.x*256 + threadIdx.x;
  if (i < n) p[i] = 0;
}

// h1 = x @ W1 ; al_s/al_d = per-head attention logits. One wave per row.
__global__ void __launch_bounds__(256) k_gemm1(const float* __restrict__ x, const float* __restrict__ W1,
        const float* __restrict__ a_s, const float* __restrict__ a_d,
        float* __restrict__ h1, float* __restrict__ al_s, float* __restrict__ al_d)
{
  __shared__ __align__(16) float Wl[IN_CHC*HCC];     // 64 KB
  __shared__ __align__(16) float xrow[4][IN_CHC];    // 2 KB
  int tid = threadIdx.x;
  for (int i = tid*4; i < IN_CHC*HCC; i += 256*4)
    *(float4*)&Wl[i] = *(const float4*)&W1[i];
  __syncthreads();
  int wave = tid >> 6, lane = tid & 63;
  int c0 = lane * 2;
  float as0 = a_s[c0], as1 = a_s[c0+1];
  float ad0 = a_d[c0], ad1 = a_d[c0+1];
  int gw = blockIdx.x*4 + wave;
  int nw = gridDim.x*4;
  for (int row = gw; row < N_NODESC; row += nw){
    float2 xv = *(const float2*)&x[(size_t)row*IN_CHC + c0];
    *(float2*)&xrow[wave][c0] = xv;
    float acc0 = 0.f, acc1 = 0.f;
    #pragma unroll 8
    for (int k = 0; k < IN_CHC; k++){
      float xk = xrow[wave][k];
      float2 w = *(const float2*)&Wl[k*HCC + c0];
      acc0 = fmaf(xk, w.x, acc0);
      acc1 = fmaf(xk, w.y, acc1);
    }
    *(float2*)&h1[(size_t)row*HCC + c0] = make_float2(acc0, acc1);
    float ps = acc0*as0 + acc1*as1;
    float pd = acc0*ad0 + acc1*ad1;
    #pragma unroll
    for (int m = 1; m < 16; m <<= 1){ ps += __shfl_xor(ps, m, 64); pd += __shfl_xor(pd, m, 64); }
    if ((lane & 15) == 0){
      al_s[row*HEADSC + (lane>>4)] = ps;
      al_d[row*HEADSC + (lane>>4)] = pd;
    }
  }
}

__global__ void __launch_bounds__(256) k_hist(const int* __restrict__ ei, int* __restrict__ deg){
  int e = blockIdx.x*256 + threadIdx.x;
  if (e < E_TOTC){
    int d = (e < E0C) ? ei[E0C + e] : (e - E0C);
    atomicAdd(&deg[d], 1);
  }
}

// exclusive scan of deg[0..N) -> rp, nxt ; rp[N] = total
__global__ void __launch_bounds__(1024) k_scan(const int* __restrict__ deg, int* __restrict__ rp, int* __restrict__ nxt){
  const int C = 49;  // 1024*49 = 50176 >= 50000
  __shared__ int buf[1024];
  int tid = threadIdx.x;
  int base = tid * C;
  int s = 0;
  for (int j = 0; j < C; j++){
    int i = base + j;
    s += (i < N_NODESC) ? deg[i] : 0;
  }
  buf[tid] = s; __syncthreads();
  for (int off = 1; off < 1024; off <<= 1){
    int t = (tid >= off) ? buf[tid - off] : 0;
    __syncthreads();
    buf[tid] += t;
    __syncthreads();
  }
  int run = buf[tid] - s;   // exclusive prefix
  for (int j = 0; j < C; j++){
    int i = base + j;
    if (i < N_NODESC){
      rp[i] = run; nxt[i] = run;
      run += deg[i];
    }
  }
  if (tid == 1023) rp[N_NODESC] = run;
}

__global__ void __launch_bounds__(256) k_scatter(const int* __restrict__ ei, int* __restrict__ nxt, int* __restrict__ srcs){
  int e = blockIdx.x*256 + threadIdx.x;
  if (e < E_TOTC){
    int s, d;
    if (e < E0C){ s = ei[e]; d = ei[E0C + e]; }
    else { s = e - E0C; d = s; }
    int pos = atomicAdd(&nxt[d], 1);
    srcs[pos] = s;
  }
}

// Layer-1 segment softmax + aggregate + bias + ELU. One wave per dst node.
__global__ void __launch_bounds__(256) k_node1(const float* __restrict__ h1,
        const float* __restrict__ al_s, const float* __restrict__ al_d,
        const int* __restrict__ rp, const int* __restrict__ srcs,
        const float* __restrict__ b1, float* __restrict__ hout)
{
  int wave = threadIdx.x >> 6, lane = threadIdx.x & 63;
  int n = blockIdx.x*4 + wave;
  if (n >= N_NODESC) return;
  int beg = rp[n], end = rp[n+1];
  float4 ad4 = *(const float4*)&al_d[n*4];
  float m0=-INFINITY, m1=-INFINITY, m2=-INFINITY, m3=-INFINITY;
  for (int p = beg + lane; p < end; p += 64){
    int s = srcs[p];
    float4 as = *(const float4*)&al_s[s*4];
    m0 = fmaxf(m0, lrelu(as.x + ad4.x));
    m1 = fmaxf(m1, lrelu(as.y + ad4.y));
    m2 = fmaxf(m2, lrelu(as.z + ad4.z));
    m3 = fmaxf(m3, lrelu(as.w + ad4.w));
  }
  #pragma unroll
  for (int o = 1; o < 64; o <<= 1){
    m0 = fmaxf(m0, __shfl_xor(m0, o, 64));
    m1 = fmaxf(m1, __shfl_xor(m1, o, 64));
    m2 = fmaxf(m2, __shfl_xor(m2, o, 64));
    m3 = fmaxf(m3, __shfl_xor(m3, o, 64));
  }
  float d0=0.f, d1=0.f, d2=0.f, d3=0.f;
  for (int p = beg + lane; p < end; p += 64){
    int s = srcs[p];
    float4 as = *(const float4*)&al_s[s*4];
    d0 += expf(lrelu(as.x + ad4.x) - m0);
    d1 += expf(lrelu(as.y + ad4.y) - m1);
    d2 += expf(lrelu(as.z + ad4.z) - m2);
    d3 += expf(lrelu(as.w + ad4.w) - m3);
  }
  #pragma unroll
  for (int o = 1; o < 64; o <<= 1){
    d0 += __shfl_xor(d0, o, 64);
    d1 += __shfl_xor(d1, o, 64);
    d2 += __shfl_xor(d2, o, 64);
    d3 += __shfl_xor(d3, o, 64);
  }
  int c0 = lane*2, h = lane >> 4;
  float mh  = (h==0) ? m0 : (h==1) ? m1 : (h==2) ? m2 : m3;
  float dh  = (h==0) ? d0 : (h==1) ? d1 : (h==2) ? d2 : d3;
  float adh = (h==0) ? ad4.x : (h==1) ? ad4.y : (h==2) ? ad4.z : ad4.w;
  float inv = 1.f / (dh + 1e-16f);
  float acc0 = 0.f, acc1 = 0.f;
  for (int p = beg; p < end; p++){
    int s = srcs[p];
    float alpha = expf(lrelu(al_s[s*4 + h] + adh) - mh) * inv;
    float2 hv = *(const float2*)&h1[(size_t)s*HCC + c0];
    acc0 = fmaf(alpha, hv.x, acc0);
    acc1 = fmaf(alpha, hv.y, acc1);
  }
  float o0 = acc0 + b1[c0], o1 = acc1 + b1[c0+1];
  o0 = o0 > 0.f ? o0 : expf(o0) - 1.f;   // ELU
  o1 = o1 > 0.f ? o1 : expf(o1) - 1.f;
  *(float2*)&hout[(size_t)n*HCC + c0] = make_float2(o0, o1);
}

// h2 = hout @ W2 ; scalar attention logits (H=1,C=16). 4 rows per wave.
__global__ void __launch_bounds__(256) k_gemm2(const float* __restrict__ hin, const float* __restrict__ W2,
        const float* __restrict__ a_s, const float* __restrict__ a_d,
        float* __restrict__ h2, float* __restrict__ al_s, float* __restrict__ al_d)
{
  __shared__ __align__(16) float Wl[IN_CHC*OUT_CHC];   // 8 KB
  __shared__ __align__(16) float xr[4][4][IN_CHC];     // 8 KB
  int tid = threadIdx.x;
  for (int i = tid*4; i < IN_CHC*OUT_CHC; i += 256*4)
    *(float4*)&Wl[i] = *(const float4*)&W2[i];
  __syncthreads();
  int wave = tid >> 6, lane = tid & 63;
  int r = lane >> 4, c = lane & 15;
  int row0 = blockIdx.x*16 + wave*4;
  for (int rr = 0; rr < 4; rr++){
    float2 v = *(const float2*)&hin[(size_t)(row0+rr)*IN_CHC + lane*2];
    *(float2*)&xr[wave][rr][lane*2] = v;
  }
  float acc = 0.f;
  #pragma unroll 8
  for (int k = 0; k < IN_CHC; k++)
    acc = fmaf(xr[wave][r][k], Wl[k*OUT_CHC + c], acc);
  int row = row0 + r;
  h2[row*OUT_CHC + c] = acc;
  float ps = acc * a_s[c];
  float pd = acc * a_d[c];
  #pragma unroll
  for (int m = 1; m < 16; m <<= 1){ ps += __shfl_xor(ps, m, 64); pd += __shfl_xor(pd, m, 64); }
  if (c == 0){ al_s[row] = ps; al_d[row] = pd; }
}

// Layer-2 segment softmax + aggregate + bias + log_softmax. One wave per dst node.
__global__ void __launch_bounds__(256) k_node2(const float* __restrict__ h2,
        const float* __restrict__ al_s, const float* __restrict__ al_d,
        const int* __restrict__ rp, const int* __restrict__ srcs,
        const float* __restrict__ b2, float* __restrict__ out)
{
  int wave = threadIdx.x >> 6, lane = threadIdx.x & 63;
  int n = blockIdx.x*4 + wave;
  if (n >= N_NODESC) return;
  int beg = rp[n], end = rp[n+1];
  float ad = al_d[n];
  float m = -INFINITY;
  for (int p = beg + lane; p < end; p += 64)
    m = fmaxf(m, lrelu(al_s[srcs[p]] + ad));
  #pragma unroll
  for (int o = 1; o < 64; o <<= 1) m = fmaxf(m, __shfl_xor(m, o, 64));
  float den = 0.f;
  for (int p = beg + lane; p < end; p += 64)
    den += expf(lrelu(al_s[srcs[p]] + ad) - m);
  #pragma unroll
  for (int o = 1; o < 64; o <<= 1) den += __shfl_xor(den, o, 64);
  float inv = 1.f / (den + 1e-16f);
  int c = lane & 15, j = lane >> 4;
  float acc = 0.f;
  for (int p = beg + j; p < end; p += 4){
    int s = srcs[p];
    float alpha = expf(lrelu(al_s[s] + ad) - m) * inv;
    acc = fmaf(alpha, h2[s*OUT_CHC + c], acc);
  }
  acc += __shfl_xor(acc, 16, 64);
  acc += __shfl_xor(acc, 32, 64);
  float v = acc + b2[c];
  float mm = v;
  #pragma unroll
  for (int o = 1; o < 16; o <<= 1) mm = fmaxf(mm, __shfl_xor(mm, o, 64));
  float se = expf(v - mm);
  #pragma unroll
  for (int o = 1; o < 16; o <<= 1) se += __shfl_xor(se, o, 64);
  if (j == 0) out[n*OUT_CHC + c] = v - mm - logf(se);
}

extern "C" void kernel_launch(void* const* d_in, const int* in_sizes, int n_in,
                              void* d_out, int out_size, void* d_ws, size_t ws_size,
                              hipStream_t stream)
{
  const float* x   = (const float*)d_in[0];
  const int*   ei  = (const int*)d_in[1];
  // d_in[2] edge_attr: ignored (PyG GATConv with edge_dim=None)
  const float* W1  = (const float*)d_in[3];
  const float* as1 = (const float*)d_in[4];
  const float* ad1 = (const float*)d_in[5];
  const float* b1  = (const float*)d_in[6];
  const float* W2  = (const float*)d_in[7];
  const float* as2 = (const float*)d_in[8];
  const float* ad2 = (const float*)d_in[9];
  const float* b2  = (const float*)d_in[10];
  float* out = (float*)d_out;

  char* ws = (char*)d_ws;
  size_t off = 0;
  auto alloc = [&](size_t bytes)->void*{
    void* p = ws + off;
    off = (off + bytes + 255) & ~(size_t)255;
    return p;
  };
  float* h1    = (float*)alloc((size_t)N_NODESC*HCC*4);
  float* hout  = (float*)alloc((size_t)N_NODESC*HCC*4);
  float* al_s1 = (float*)alloc((size_t)N_NODESC*HEADSC*4);
  float* al_d1 = (float*)alloc((size_t)N_NODESC*HEADSC*4);
  float* h2    = (float*)alloc((size_t)N_NODESC*OUT_CHC*4);
  float* al_s2 = (float*)alloc((size_t)N_NODESC*4);
  float* al_d2 = (float*)alloc((size_t)N_NODESC*4);
  int* deg     = (int*)alloc((size_t)N_NODESC*4);
  int* rp      = (int*)alloc((size_t)(N_NODESC+1)*4);
  int* nxt     = (int*)alloc((size_t)N_NODESC*4);
  int* srcs    = (int*)alloc((size_t)E_TOTC*4);

  k_zero<<<(N_NODESC+255)/256, 256, 0, stream>>>(deg, N_NODESC);
  k_gemm1<<<1024, 256, 0, stream>>>(x, W1, as1, ad1, h1, al_s1, al_d1);
  k_hist<<<(E_TOTC+255)/256, 256, 0, stream>>>(ei, deg);
  k_scan<<<1, 1024, 0, stream>>>(deg, rp, nxt);
  k_scatter<<<(E_TOTC+255)/256, 256, 0, stream>>>(ei, nxt, srcs);
  k_node1<<<(N_NODESC+3)/4, 256, 0, stream>>>(h1, al_s1, al_d1, rp, srcs, b1, hout);
  k_gemm2<<<N_NODESC/16, 256, 0, stream>>>(hout, W2, as2, ad2, h2, al_s2, al_d2);
  k_node2<<<(N_NODESC+3)/4, 256, 0, stream>>>(h2, al_s2, al_d2, rp, srcs, b2, out);
}

// Round 2
// 348.356 us; speedup vs baseline: 1.3335x; 1.3335x over previous
//
#include <hip/hip_runtime.h>

#define N_NODESC 50000
#define E0C      800000
#define E_TOTC   850000
#define IN_CHC   128
#define HCC      128   // HEADS*HID
#define HEADSC   4
#define OUT_CHC  16
#define NEG_SLOPE 0.2f
#define NBLK     ((N_NODESC + 255) / 256)   // 196

__device__ __forceinline__ float lrelu(float v){ return v > 0.f ? v : NEG_SLOPE * v; }

__global__ void __launch_bounds__(256) k_zero(int* __restrict__ p, int n){
  int i = blockIdx.x*256 + threadIdx.x;
  if (i < n) p[i] = 0;
}

// h1 = x @ W1 ; al_s/al_d = per-head attention logits. One wave per row.
__global__ void __launch_bounds__(256) k_gemm1(const float* __restrict__ x, const float* __restrict__ W1,
        const float* __restrict__ a_s, const float* __restrict__ a_d,
        float* __restrict__ h1, float* __restrict__ al_s, float* __restrict__ al_d)
{
  __shared__ __align__(16) float Wl[IN_CHC*HCC];     // 64 KB
  __shared__ __align__(16) float xrow[4][IN_CHC];    // 2 KB
  int tid = threadIdx.x;
  for (int i = tid*4; i < IN_CHC*HCC; i += 256*4)
    *(float4*)&Wl[i] = *(const float4*)&W1[i];
  __syncthreads();
  int wave = tid >> 6, lane = tid & 63;
  int c0 = lane * 2;
  float as0 = a_s[c0], as1 = a_s[c0+1];
  float ad0 = a_d[c0], ad1 = a_d[c0+1];
  int gw = blockIdx.x*4 + wave;
  int nw = gridDim.x*4;
  for (int row = gw; row < N_NODESC; row += nw){
    float2 xv = *(const float2*)&x[(size_t)row*IN_CHC + c0];
    *(float2*)&xrow[wave][c0] = xv;
    float acc0 = 0.f, acc1 = 0.f;
    #pragma unroll 8
    for (int k = 0; k < IN_CHC; k++){
      float xk = xrow[wave][k];
      float2 w = *(const float2*)&Wl[k*HCC + c0];
      acc0 = fmaf(xk, w.x, acc0);
      acc1 = fmaf(xk, w.y, acc1);
    }
    *(float2*)&h1[(size_t)row*HCC + c0] = make_float2(acc0, acc1);
    float ps = acc0*as0 + acc1*as1;
    float pd = acc0*ad0 + acc1*ad1;
    #pragma unroll
    for (int m = 1; m < 16; m <<= 1){ ps += __shfl_xor(ps, m, 64); pd += __shfl_xor(pd, m, 64); }
    if ((lane & 15) == 0){
      al_s[row*HEADSC + (lane>>4)] = ps;
      al_d[row*HEADSC + (lane>>4)] = pd;
    }
  }
}

__global__ void __launch_bounds__(256) k_hist(const int* __restrict__ ei, int* __restrict__ deg){
  int e = blockIdx.x*256 + threadIdx.x;
  if (e < E_TOTC){
    int d = (e < E0C) ? ei[E0C + e] : (e - E0C);
    atomicAdd(&deg[d], 1);
  }
}

// --- multi-block exclusive scan of deg -> rp, nxt ---
__global__ void __launch_bounds__(256) k_blocksum(const int* __restrict__ deg, int* __restrict__ bsum){
  int i = blockIdx.x*256 + threadIdx.x;
  int v = (i < N_NODESC) ? deg[i] : 0;
  #pragma unroll
  for (int o = 1; o < 64; o <<= 1) v += __shfl_xor(v, o, 64);
  __shared__ int ws[4];
  if ((threadIdx.x & 63) == 0) ws[threadIdx.x >> 6] = v;
  __syncthreads();
  if (threadIdx.x == 0) bsum[blockIdx.x] = ws[0] + ws[1] + ws[2] + ws[3];
}

__global__ void __launch_bounds__(256) k_scanbsum(const int* __restrict__ bsum, int* __restrict__ boff, int* __restrict__ rp_last){
  __shared__ int buf[256];
  int tid = threadIdx.x;
  int v = (tid < NBLK) ? bsum[tid] : 0;
  buf[tid] = v; __syncthreads();
  #pragma unroll
  for (int off = 1; off < 256; off <<= 1){
    int t = (tid >= off) ? buf[tid - off] : 0;
    __syncthreads();
    buf[tid] += t; __syncthreads();
  }
  if (tid < NBLK) boff[tid] = buf[tid] - v;  // exclusive
  if (tid == 255) rp_last[0] = buf[255];     // total = rp[N]
}

__global__ void __launch_bounds__(256) k_scanblock(const int* __restrict__ deg, const int* __restrict__ boff,
                                                   int* __restrict__ rp, int* __restrict__ nxt){
  __shared__ int buf[256];
  int tid = threadIdx.x;
  int i = blockIdx.x*256 + tid;
  int v = (i < N_NODESC) ? deg[i] : 0;
  buf[tid] = v; __syncthreads();
  #pragma unroll
  for (int off = 1; off < 256; off <<= 1){
    int t = (tid >= off) ? buf[tid - off] : 0;
    __syncthreads();
    buf[tid] += t; __syncthreads();
  }
  if (i < N_NODESC){
    int ex = boff[blockIdx.x] + buf[tid] - v;
    rp[i] = ex; nxt[i] = ex;
  }
}

__global__ void __launch_bounds__(256) k_scatter(const int* __restrict__ ei, int* __restrict__ nxt, int* __restrict__ srcs){
  int e = blockIdx.x*256 + threadIdx.x;
  if (e < E_TOTC){
    int s, d;
    if (e < E0C){ s = ei[e]; d = ei[E0C + e]; }
    else { s = e - E0C; d = s; }
    int pos = atomicAdd(&nxt[d], 1);
    srcs[pos] = s;
  }
}

// Layer-1 segment softmax + aggregate + bias + ELU. One wave per dst node.
__global__ void __launch_bounds__(256) k_node1(const float* __restrict__ h1,
        const float* __restrict__ al_s, const float* __restrict__ al_d,
        const int* __restrict__ rp, const int* __restrict__ srcs,
        const float* __restrict__ b1, float* __restrict__ hout)
{
  int wave = threadIdx.x >> 6, lane = threadIdx.x & 63;
  int n = blockIdx.x*4 + wave;
  if (n >= N_NODESC) return;
  int beg = rp[n], end = rp[n+1];
  float4 ad4 = *(const float4*)&al_d[n*4];
  float m0=-INFINITY, m1=-INFINITY, m2=-INFINITY, m3=-INFINITY;
  for (int p = beg + lane; p < end; p += 64){
    int s = srcs[p];
    float4 as = *(const float4*)&al_s[s*4];
    m0 = fmaxf(m0, lrelu(as.x + ad4.x));
    m1 = fmaxf(m1, lrelu(as.y + ad4.y));
    m2 = fmaxf(m2, lrelu(as.z + ad4.z));
    m3 = fmaxf(m3, lrelu(as.w + ad4.w));
  }
  #pragma unroll
  for (int o = 1; o < 64; o <<= 1){
    m0 = fmaxf(m0, __shfl_xor(m0, o, 64));
    m1 = fmaxf(m1, __shfl_xor(m1, o, 64));
    m2 = fmaxf(m2, __shfl_xor(m2, o, 64));
    m3 = fmaxf(m3, __shfl_xor(m3, o, 64));
  }
  float d0=0.f, d1=0.f, d2=0.f, d3=0.f;
  for (int p = beg + lane; p < end; p += 64){
    int s = srcs[p];
    float4 as = *(const float4*)&al_s[s*4];
    d0 += expf(lrelu(as.x + ad4.x) - m0);
    d1 += expf(lrelu(as.y + ad4.y) - m1);
    d2 += expf(lrelu(as.z + ad4.z) - m2);
    d3 += expf(lrelu(as.w + ad4.w) - m3);
  }
  #pragma unroll
  for (int o = 1; o < 64; o <<= 1){
    d0 += __shfl_xor(d0, o, 64);
    d1 += __shfl_xor(d1, o, 64);
    d2 += __shfl_xor(d2, o, 64);
    d3 += __shfl_xor(d3, o, 64);
  }
  int c0 = lane*2, h = lane >> 4;
  float mh  = (h==0) ? m0 : (h==1) ? m1 : (h==2) ? m2 : m3;
  float dh  = (h==0) ? d0 : (h==1) ? d1 : (h==2) ? d2 : d3;
  float adh = (h==0) ? ad4.x : (h==1) ? ad4.y : (h==2) ? ad4.z : ad4.w;
  float inv = 1.f / (dh + 1e-16f);
  float acc0 = 0.f, acc1 = 0.f;
  for (int p = beg; p < end; p++){
    int s = srcs[p];
    float alpha = expf(lrelu(al_s[s*4 + h] + adh) - mh) * inv;
    float2 hv = *(const float2*)&h1[(size_t)s*HCC + c0];
    acc0 = fmaf(alpha, hv.x, acc0);
    acc1 = fmaf(alpha, hv.y, acc1);
  }
  float o0 = acc0 + b1[c0], o1 = acc1 + b1[c0+1];
  o0 = o0 > 0.f ? o0 : expf(o0) - 1.f;   // ELU
  o1 = o1 > 0.f ? o1 : expf(o1) - 1.f;
  *(float2*)&hout[(size_t)n*HCC + c0] = make_float2(o0, o1);
}

// h2 = hout @ W2 ; scalar attention logits (H=1,C=16). 4 rows per wave.
__global__ void __launch_bounds__(256) k_gemm2(const float* __restrict__ hin, const float* __restrict__ W2,
        const float* __restrict__ a_s, const float* __restrict__ a_d,
        float* __restrict__ h2, float* __restrict__ al_s, float* __restrict__ al_d)
{
  __shared__ __align__(16) float Wl[IN_CHC*OUT_CHC];   // 8 KB
  __shared__ __align__(16) float xr[4][4][IN_CHC];     // 8 KB
  int tid = threadIdx.x;
  for (int i = tid*4; i < IN_CHC*OUT_CHC; i += 256*4)
    *(float4*)&Wl[i] = *(const float4*)&W2[i];
  __syncthreads();
  int wave = tid >> 6, lane = tid & 63;
  int r = lane >> 4, c = lane & 15;
  int row0 = blockIdx.x*16 + wave*4;
  for (int rr = 0; rr < 4; rr++){
    float2 v = *(const float2*)&hin[(size_t)(row0+rr)*IN_CHC + lane*2];
    *(float2*)&xr[wave][rr][lane*2] = v;
  }
  float acc = 0.f;
  #pragma unroll 8
  for (int k = 0; k < IN_CHC; k++)
    acc = fmaf(xr[wave][r][k], Wl[k*OUT_CHC + c], acc);
  int row = row0 + r;
  h2[row*OUT_CHC + c] = acc;
  float ps = acc * a_s[c];
  float pd = acc * a_d[c];
  #pragma unroll
  for (int m = 1; m < 16; m <<= 1){ ps += __shfl_xor(ps, m, 64); pd += __shfl_xor(pd, m, 64); }
  if (c == 0){ al_s[row] = ps; al_d[row] = pd; }
}

// Layer-2 segment softmax + aggregate + bias + log_softmax. One wave per dst node.
__global__ void __launch_bounds__(256) k_node2(const float* __restrict__ h2,
        const float* __restrict__ al_s, const float* __restrict__ al_d,
        const int* __restrict__ rp, const int* __restrict__ srcs,
        const float* __restrict__ b2, float* __restrict__ out)
{
  int wave = threadIdx.x >> 6, lane = threadIdx.x & 63;
  int n = blockIdx.x*4 + wave;
  if (n >= N_NODESC) return;
  int beg = rp[n], end = rp[n+1];
  float ad = al_d[n];
  float m = -INFINITY;
  for (int p = beg + lane; p < end; p += 64)
    m = fmaxf(m, lrelu(al_s[srcs[p]] + ad));
  #pragma unroll
  for (int o = 1; o < 64; o <<= 1) m = fmaxf(m, __shfl_xor(m, o, 64));
  float den = 0.f;
  for (int p = beg + lane; p < end; p += 64)
    den += expf(lrelu(al_s[srcs[p]] + ad) - m);
  #pragma unroll
  for (int o = 1; o < 64; o <<= 1) den += __shfl_xor(den, o, 64);
  float inv = 1.f / (den + 1e-16f);
  int c = lane & 15, j = lane >> 4;
  float acc = 0.f;
  for (int p = beg + j; p < end; p += 4){
    int s = srcs[p];
    float alpha = expf(lrelu(al_s[s] + ad) - m) * inv;
    acc = fmaf(alpha, h2[s*OUT_CHC + c], acc);
  }
  acc += __shfl_xor(acc, 16, 64);
  acc += __shfl_xor(acc, 32, 64);
  float v = acc + b2[c];
  float mm = v;
  #pragma unroll
  for (int o = 1; o < 16; o <<= 1) mm = fmaxf(mm, __shfl_xor(mm, o, 64));
  float se = expf(v - mm);
  #pragma unroll
  for (int o = 1; o < 16; o <<= 1) se += __shfl_xor(se, o, 64);
  if (j == 0) out[n*OUT_CHC + c] = v - mm - logf(se);
}

extern "C" void kernel_launch(void* const* d_in, const int* in_sizes, int n_in,
                              void* d_out, int out_size, void* d_ws, size_t ws_size,
                              hipStream_t stream)
{
  const float* x   = (const float*)d_in[0];
  const int*   ei  = (const int*)d_in[1];
  // d_in[2] edge_attr: ignored (PyG GATConv with edge_dim=None)
  const float* W1  = (const float*)d_in[3];
  const float* as1 = (const float*)d_in[4];
  const float* ad1 = (const float*)d_in[5];
  const float* b1  = (const float*)d_in[6];
  const float* W2  = (const float*)d_in[7];
  const float* as2 = (const float*)d_in[8];
  const float* ad2 = (const float*)d_in[9];
  const float* b2  = (const float*)d_in[10];
  float* out = (float*)d_out;

  char* ws = (char*)d_ws;
  size_t off = 0;
  auto alloc = [&](size_t bytes)->void*{
    void* p = ws + off;
    off = (off + bytes + 255) & ~(size_t)255;
    return p;
  };
  float* h1    = (float*)alloc((size_t)N_NODESC*HCC*4);
  float* hout  = (float*)alloc((size_t)N_NODESC*HCC*4);
  float* al_s1 = (float*)alloc((size_t)N_NODESC*HEADSC*4);
  float* al_d1 = (float*)alloc((size_t)N_NODESC*HEADSC*4);
  float* h2    = (float*)alloc((size_t)N_NODESC*OUT_CHC*4);
  float* al_s2 = (float*)alloc((size_t)N_NODESC*4);
  float* al_d2 = (float*)alloc((size_t)N_NODESC*4);
  int* deg     = (int*)alloc((size_t)N_NODESC*4);
  int* rp      = (int*)alloc((size_t)(N_NODESC+1)*4);
  int* nxt     = (int*)alloc((size_t)N_NODESC*4);
  int* srcs    = (int*)alloc((size_t)E_TOTC*4);
  int* bsum    = (int*)alloc((size_t)NBLK*4);
  int* boff    = (int*)alloc((size_t)NBLK*4);

  k_zero<<<(N_NODESC+255)/256, 256, 0, stream>>>(deg, N_NODESC);
  k_gemm1<<<1024, 256, 0, stream>>>(x, W1, as1, ad1, h1, al_s1, al_d1);
  k_hist<<<(E_TOTC+255)/256, 256, 0, stream>>>(ei, deg);
  k_blocksum<<<NBLK, 256, 0, stream>>>(deg, bsum);
  k_scanbsum<<<1, 256, 0, stream>>>(bsum, boff, rp + N_NODESC);
  k_scanblock<<<NBLK, 256, 0, stream>>>(deg, boff, rp, nxt);
  k_scatter<<<(E_TOTC+255)/256, 256, 0, stream>>>(ei, nxt, srcs);
  k_node1<<<(N_NODESC+3)/4, 256, 0, stream>>>(h1, al_s1, al_d1, rp, srcs, b1, hout);
  k_gemm2<<<N_NODESC/16, 256, 0, stream>>>(hout, W2, as2, ad2, h2, al_s2, al_d2);
  k_node2<<<(N_NODESC+3)/4, 256, 0, stream>>>(h2, al_s2, al_d2, rp, srcs, b2, out);
}